// Round 17
// baseline (211.362 us; speedup 1.0000x reference)
//
#include <hip/hip_runtime.h>

// Problem constants (B=2, S=2048, D=2048), all tile-divisible.
#define DM  2048
#define SQ  2048
#define NB  2
#define BSZ (NB * SQ)   // 4096 flattened tokens

typedef _Float16 f16x8 __attribute__((ext_vector_type(8)));
typedef __attribute__((ext_vector_type(4))) float f32x4;

#define ASG(p) (const __attribute__((address_space(1))) void*)(p)
#define ASL(p) (__attribute__((address_space(3))) void*)(p)

__device__ __forceinline__ unsigned short f2h(float f) {
  union { _Float16 h; unsigned short u; } x;
  x.h = (_Float16)f;  // v_cvt_f16_f32, RNE
  return x.u;
}
__device__ __forceinline__ float h2f(unsigned short u) {
  union { unsigned short u; _Float16 h; } x;
  x.u = u;
  return (float)x.h;
}

// ---- straight fp32->fp16 cast: x (n4x float4s) then Wo (n4w), contiguous out.
__global__ __launch_bounds__(256) void cast_x_wo(const float4* __restrict__ x,
                                                 const float4* __restrict__ wo,
                                                 ushort4* __restrict__ outx,
                                                 ushort4* __restrict__ outwo,
                                                 int n4x, int n4w) {
  int i = blockIdx.x * 256 + threadIdx.x;
  float4 v;
  ushort4* dst;
  int j;
  if (i < n4x) { v = x[i]; dst = outx; j = i; }
  else { j = i - n4x; if (j >= n4w) return; v = wo[j]; dst = outwo; }
  ushort4 h;
  h.x = f2h(v.x); h.y = f2h(v.y); h.z = f2h(v.z); h.w = f2h(v.w);
  dst[j] = h;
}

// ---- transpose-cast: W f32 [2048][2048] (d,e) -> WT fp16 [2048][2048] (e,d).
// 64x64 tiles, 256 threads. z selects {Wq,Wk,Wv}.
__global__ __launch_bounds__(256) void cast_t(const float* __restrict__ wq,
                                              const float* __restrict__ wk,
                                              const float* __restrict__ wv,
                                              unsigned short* __restrict__ wqT,
                                              unsigned short* __restrict__ wkT,
                                              unsigned short* __restrict__ wvT) {
  __shared__ unsigned short tile[64][66];
  const float* in = (blockIdx.z == 0) ? wq : (blockIdx.z == 1) ? wk : wv;
  unsigned short* outT = (blockIdx.z == 0) ? wqT : (blockIdx.z == 1) ? wkT : wvT;
  const int tid = threadIdx.x;
  const int d0 = blockIdx.x * 64, e0 = blockIdx.y * 64;
  const int r = tid >> 4;          // 0..15
  const int c = (tid & 15) * 4;    // 0..60
#pragma unroll
  for (int p = 0; p < 4; p++) {
    const int dl = r + p * 16;
    float4 v = *(const float4*)&in[(long)(d0 + dl) * DM + e0 + c];
    tile[c + 0][dl] = f2h(v.x);
    tile[c + 1][dl] = f2h(v.y);
    tile[c + 2][dl] = f2h(v.z);
    tile[c + 3][dl] = f2h(v.w);
  }
  __syncthreads();
  const int r2 = tid >> 3;         // 0..31
  const int c2 = (tid & 7) * 8;    // 0..56
#pragma unroll
  for (int p = 0; p < 2; p++) {
    const int el = r2 + p * 32;
    union { uint4 u4; unsigned short us[8]; } o;
#pragma unroll
    for (int k = 0; k < 8; k++) o.us[k] = tile[el][c2 + k];
    *(uint4*)&outT[(long)(e0 + el) * DM + d0 + c2] = o.u4;
  }
}

#define SB() __builtin_amdgcn_sched_barrier(0)
#define BARX() do { SB(); __builtin_amdgcn_s_barrier(); SB(); } while (0)

// ============================================================================
// 128x128 GEMM engine body (R11 schedule EXACTLY — verified race-free over
// R11-R16 replays). 256 thr = 4 waves (2Mx2N), per-wave 64x64, BK=64,
// dbuf 2x32KB LDS, XOR swizzle (16B slot ^= row&7) both-sides (rule #21).
// Windows/hazards/vmcnt(6)/(0) ledger: see R11 commentary.
// ============================================================================
#define STAGEK(BUFL, REG, U, T) do { \
    const unsigned short* G_ = (REG) ? Bb : Ab; \
    const int ldG_ = (REG) ? ldB : ldA; \
    const int r0_ = ((REG) ? bn0 : bm0) + (U) * 32; \
    const long k0_ = (long)((T) << 6); \
    char* db_ = ldsb + (BUFL) * 32768 + (REG) * 16384 + (U) * 4096 + tid * 16; \
    const unsigned short* s_ = G_ + (long)(r0_ + srow) * ldG_ + k0_ + scsw; \
    __builtin_amdgcn_global_load_lds(ASG(s_), ASL(db_), 16, 0, 0); \
  } while (0)

#define LDAK(BUFL, MH, Af) do { \
    const char* ba_ = ldsb + (BUFL) * 32768 + (wm * 64 + (MH) * 32) * 128 + arow; \
    _Pragma("unroll") for (int mm_ = 0; mm_ < 2; mm_++) { \
      Af[mm_][0] = *(const f16x8*)(ba_ + mm_ * 2048 + sl0); \
      Af[mm_][1] = *(const f16x8*)(ba_ + mm_ * 2048 + sl1); } \
  } while (0)

#define LDBK(BUFL, NH, Bf) do { \
    const char* bb_ = ldsb + (BUFL) * 32768 + 16384 + (wn * 64 + (NH) * 32) * 128 + arow; \
    _Pragma("unroll") for (int nn_ = 0; nn_ < 2; nn_++) { \
      Bf[nn_][0] = *(const f16x8*)(bb_ + nn_ * 2048 + sl0); \
      Bf[nn_][1] = *(const f16x8*)(bb_ + nn_ * 2048 + sl1); } \
  } while (0)

#define PHK(Af, Bf, MH, NH) do { \
    __builtin_amdgcn_s_setprio(1); \
    _Pragma("unroll") for (int mm_ = 0; mm_ < 2; mm_++) \
    _Pragma("unroll") for (int nn_ = 0; nn_ < 2; nn_++) \
    _Pragma("unroll") for (int ks_ = 0; ks_ < 2; ks_++) \
      acc[(MH) * 2 + mm_][(NH) * 2 + nn_] = __builtin_amdgcn_mfma_f32_16x16x32_f16( \
          Af[mm_][ks_], Bf[nn_][ks_], acc[(MH) * 2 + mm_][(NH) * 2 + nn_], 0, 0, 0); \
    __builtin_amdgcn_s_setprio(0); \
  } while (0)

#define GROUPK(BUFL, T) do { \
    LDAK(BUFL, 0, a0); LDBK(BUFL, 0, b0); \
    LDAK(BUFL, 1, a1); \
    if ((T) + 1 < NT) { STAGEK((BUFL) ^ 1, 1, 2, (T) + 1); STAGEK((BUFL) ^ 1, 1, 3, (T) + 1); } \
    PHK(a0, b0, 0, 0); \
    BARX(); \
    LDBK(BUFL, 1, b1); \
    PHK(a1, b0, 1, 0); \
    BARX(); \
    if ((T) + 2 < NT) { STAGEK(BUFL, 0, 0, (T) + 2); STAGEK(BUFL, 0, 1, (T) + 2); \
                        STAGEK(BUFL, 0, 2, (T) + 2); STAGEK(BUFL, 0, 3, (T) + 2); } \
    PHK(a1, b1, 1, 1); \
    BARX(); \
    if ((T) + 2 < NT) { STAGEK(BUFL, 1, 0, (T) + 2); STAGEK(BUFL, 1, 1, (T) + 2); } \
    PHK(a0, b1, 0, 1); \
    SB(); \
    if ((T) + 1 < NT) { \
      if ((T) + 1 == NT - 1) { asm volatile("s_waitcnt vmcnt(0)" ::: "memory"); } \
      else                   { asm volatile("s_waitcnt vmcnt(6)" ::: "memory"); } \
    } \
    __builtin_amdgcn_s_barrier(); \
    SB(); \
  } while (0)

template <int OM>
__device__ __forceinline__ void gemm128_body(
    char* ldsb, const unsigned short* __restrict__ Ab,
    const unsigned short* __restrict__ Bb,
    float* __restrict__ Cf, unsigned short* __restrict__ Ch, long cb,
    int NT, int ldA, int ldB, int ldC, int bm0, int bn0, float alpha) {
  const int tid = threadIdx.x, lane = tid & 63, wid = tid >> 6;
  const int wm = wid >> 1, wn = wid & 1;
  const int fr = lane & 15, fq = lane >> 4;

  const int sl0 = ((fq ^ (fr & 7)) << 4);
  const int sl1 = (((4 + fq) ^ (fr & 7)) << 4);
  const int arow = fr << 7;

  const int srow = tid >> 3;                       // [0,32)
  const int scsw = ((tid & 7) ^ (srow & 7)) << 3;  // inverse-swizzled global col

  f32x4 acc[4][4];
#pragma unroll
  for (int m = 0; m < 4; m++)
#pragma unroll
    for (int n = 0; n < 4; n++)
#pragma unroll
      for (int r = 0; r < 4; r++) acc[m][n][r] = 0.f;

  f16x8 a0[2][2], a1[2][2], b0[2][2], b1[2][2];

  STAGEK(0, 0, 0, 0); STAGEK(0, 0, 1, 0); STAGEK(0, 0, 2, 0); STAGEK(0, 0, 3, 0);
  STAGEK(0, 1, 0, 0); STAGEK(0, 1, 1, 0); STAGEK(0, 1, 2, 0); STAGEK(0, 1, 3, 0);
  STAGEK(1, 0, 0, 1); STAGEK(1, 0, 1, 1); STAGEK(1, 0, 2, 1); STAGEK(1, 0, 3, 1);
  STAGEK(1, 1, 0, 1); STAGEK(1, 1, 1, 1);
  asm volatile("s_waitcnt vmcnt(6)" ::: "memory");
  __builtin_amdgcn_s_barrier();
  SB();

  for (int t = 0; t < NT; t += 2) {
    GROUPK(0, t);
    GROUPK(1, t + 1);
  }

#pragma unroll
  for (int mh = 0; mh < 2; mh++)
#pragma unroll
    for (int mm = 0; mm < 2; mm++)
#pragma unroll
      for (int nh = 0; nh < 2; nh++)
#pragma unroll
        for (int nn = 0; nn < 2; nn++) {
          const int col = bn0 + wn * 64 + nh * 32 + nn * 16 + fr;
#pragma unroll
          for (int r = 0; r < 4; r++) {
            const long row = (long)bm0 + wm * 64 + mh * 32 + mm * 16 + fq * 4 + r;
            const long ci = cb + row * ldC + col;
            const float vv = acc[mh * 2 + mm][nh * 2 + nn][r] * alpha;
            if constexpr (OM == 0) Cf[ci] = vv;
            else                   Ch[ci] = f2h(vv);
          }
        }
}

// Merged dispatch A: MT = Wk^T*Wq fold (z=0) || G = Wo*Wv fold (z=1).
// 512 blocks = full fill. All operands [2048][2048] fp16 K-contig.
__global__ __launch_bounds__(256, 2) void k_mt_g(
    const unsigned short* __restrict__ wkT, const unsigned short* __restrict__ wqT,
    const unsigned short* __restrict__ wo16, const unsigned short* __restrict__ wvT,
    unsigned short* __restrict__ MT, unsigned short* __restrict__ G) {
  __shared__ __align__(16) char ldsarr[65536];
  const int bm0 = blockIdx.x * 128;
  const int bn0 = blockIdx.y * 128;
  if (blockIdx.z == 0)
    gemm128_body<1>(ldsarr, wkT, wqT, nullptr, MT, 0L, DM >> 6, DM, DM, DM, bm0, bn0, 1.0f);
  else
    gemm128_body<1>(ldsarr, wo16, wvT, nullptr, G, 0L, DM >> 6, DM, DM, DM, bm0, bn0, 1.0f);
}

// y = x*(MT)^T: [4096][2048], 512 blocks = 1 clean full-rate round.
__global__ __launch_bounds__(256, 2) void k_y(
    const unsigned short* __restrict__ x16, const unsigned short* __restrict__ MT,
    unsigned short* __restrict__ y) {
  __shared__ __align__(16) char ldsarr[65536];
  const int bm0 = blockIdx.x * 128;   // s: 32
  const int bn0 = blockIdx.y * 128;   // f: 16
  gemm128_body<1>(ldsarr, x16, MT, nullptr, y, 0L, DM >> 6, DM, DM, DM, bm0, bn0, 1.0f);
}

// Merged dispatch (R17): uT (512 tiles) + triangular-packed causal scores
// (272 active tiles), linear 784-block grid, ALL blocks uniform full-K 32
// K-tiles -> exactly 2 full-rate rounds (~37.5us), replacing the sequential
// uT-round (37.5) + scores dispatch (37.5 — unfixable alone: lone blocks run
// at half rate, so 272 tiles over 256 CUs is 37.5 regardless of mapping).
// uT[i][t] = sum_e G[i][e]*x16[t][e]; scores[b][s][t] = scale*sum_f y*x.
// No data overlap: uT reads G,x16 / writes uT; scores reads y,x16 / writes
// scores (aliases dead wqT∪wkT). x16 shared read-only.
__global__ __launch_bounds__(256, 2) void k_su(
    const unsigned short* __restrict__ G, const unsigned short* __restrict__ x16,
    const unsigned short* __restrict__ y,
    unsigned short* __restrict__ uT, unsigned short* __restrict__ scores,
    float scale) {
  __shared__ __align__(16) char ldsarr[65536];
  const int b = blockIdx.x;           // 0..783
  if (b < 512) {
    const int bm0 = (b >> 5) * 128;   // i: 16 tiles
    const int bn0 = (b & 31) * 128;   // t: 32 tiles
    gemm128_body<1>(ldsarr, G, x16, nullptr, uT, 0L, DM >> 6, DM, DM, BSZ, bm0, bn0, 1.0f);
  } else {
    const int u = b - 512;            // 0..271
    const long z = u / 136;           // batch
    const int t = u % 136;            // triangular index
    const int r = (int)((sqrtf(8.f * (float)t + 1.f) - 1.f) * 0.5f);
    const int c = t - ((r * (r + 1)) >> 1);
    const unsigned short* Ab = y   + z * (long)SQ * DM;
    const unsigned short* Bb = x16 + z * (long)SQ * DM;
    gemm128_body<1>(ldsarr, Ab, Bb, nullptr, scores, z * (long)SQ * SQ,
                    DM >> 6, DM, DM, SQ, r * 128, c * 128, scale);
  }
}

// PV/out, complementary-row pairing at full occupancy (R16, kept): grid
// (8,16,4) = 512 blocks (2/CU). z&1 = batch; z>>1 selects row x or 15-x.
// Launch pairing (i,i+256) -> each CU gets rows x and 15-x = uniform 34
// K-tiles. K-limited: NT = 2(row+1), even, >=2.
__global__ __launch_bounds__(256, 2) void k_out(
    const unsigned short* __restrict__ probs, const unsigned short* __restrict__ uT,
    float* __restrict__ out) {
  __shared__ __align__(16) char ldsarr[65536];
  const int x = blockIdx.x;            // 0..7
  const int bn0 = blockIdx.y * 128;
  const long z = blockIdx.z & 1;       // batch
  const int row = (blockIdx.z >> 1) ? (15 - x) : x;
  const unsigned short* Ab = probs + z * (long)SQ * SQ;
  const unsigned short* Bb = uT + z * 2048;
  gemm128_body<0>(ldsarr, Ab, Bb, out, nullptr, z * (long)SQ * DM,
                  2 * (row + 1), SQ, BSZ, DM, 128 * row, bn0, 1.0f);
}

// ---- causal row softmax: scores fp16 [NB*SQ][SQ] -> probs fp16, zeros t>s.
__global__ __launch_bounds__(256) void softmax_causal(const unsigned short* __restrict__ sc,
                                                      unsigned short* __restrict__ pr) {
  const int row = blockIdx.x;       // b*SQ + s
  const int s = row & (SQ - 1);
  const long base = (long)row * SQ;
  const int n = s + 1;              // valid prefix length
  const int tid = threadIdx.x;
  const int lane = tid & 63;
  const int wv = tid >> 6;
  const int e0 = tid * 8;
  __shared__ float red[4];

  union { uint4 u4; unsigned short us[8]; } in, ou;
  in.u4 = *(const uint4*)&sc[base + e0];

  float v[8];
  float mx = -3.0e38f;
#pragma unroll
  for (int j = 0; j < 8; j++) {
    v[j] = (e0 + j < n) ? h2f(in.us[j]) : -3.0e38f;  // mask BEFORE use
    mx = fmaxf(mx, v[j]);
  }
#pragma unroll
  for (int o = 32; o >= 1; o >>= 1) mx = fmaxf(mx, __shfl_xor(mx, o));
  if (lane == 0) red[wv] = mx;
  __syncthreads();
  mx = fmaxf(fmaxf(red[0], red[1]), fmaxf(red[2], red[3]));
  __syncthreads();

  float sum = 0.f;
#pragma unroll
  for (int j = 0; j < 8; j++) {
    v[j] = (e0 + j < n) ? __expf(v[j] - mx) : 0.f;
    sum += v[j];
  }
#pragma unroll
  for (int o = 32; o >= 1; o >>= 1) sum += __shfl_xor(sum, o);
  if (lane == 0) red[wv] = sum;
  __syncthreads();
  const float inv = 1.f / (red[0] + red[1] + red[2] + red[3]);
#pragma unroll
  for (int j = 0; j < 8; j++) ou.us[j] = (e0 + j < n) ? f2h(v[j] * inv) : (unsigned short)0;
  *(uint4*)&pr[base + e0] = ou.u4;
}

extern "C" void kernel_launch(void* const* d_in, const int* in_sizes, int n_in,
                              void* d_out, int out_size, void* d_ws, size_t ws_size,
                              hipStream_t stream) {
  (void)in_sizes; (void)n_in; (void)out_size; (void)ws_size;
  const float* x  = (const float*)d_in[0];
  // d_in[1] = mask: exactly causal-additive(-1e9) -> implemented structurally.
  const float* Wq = (const float*)d_in[2];
  const float* Wk = (const float*)d_in[3];
  const float* Wv = (const float*)d_in[4];
  const float* Wo = (const float*)d_in[5];
  float* out = (float*)d_out;

  const long ELx = (long)BSZ * DM;  // 8,388,608
  const long ELw = (long)DM * DM;   // 4,194,304

  char* ws = (char*)d_ws;
  size_t off = 0;
  auto take = [&](size_t bytes) { void* p = ws + off; off += bytes; return p; };

  unsigned short* x16  = (unsigned short*)take(ELx * 2);  // dead after k_su
  unsigned short* wqT  = (unsigned short*)take(ELw * 2);  // dead after k_mt_g
  unsigned short* wkT  = (unsigned short*)take(ELw * 2);  // dead after k_mt_g
  unsigned short* wvT  = (unsigned short*)take(ELw * 2);  // dead after k_mt_g
  unsigned short* wo16 = (unsigned short*)take(ELw * 2);  // dead after k_mt_g
  unsigned short* MT   = (unsigned short*)take(ELw * 2);  // dead after k_y
  unsigned short* G    = (unsigned short*)take(ELw * 2);  // dead after k_su
  unsigned short* y    = (unsigned short*)take(ELx * 2);  // dead after k_su
  unsigned short* uT   = (unsigned short*)take(ELx * 2);  // live till k_out
  unsigned short* probs = (unsigned short*)take((long)NB * SQ * SQ * 2);
  // scores (16 MiB = NB*SQ*SQ fp16) aliases wqT∪wkT exactly (both dead after
  // k_mt_g; scores written two dispatches later — stream-ordered).
  unsigned short* scores = wqT;

  const int n4x = (int)(ELx / 4), n4w = (int)(ELw / 4);
  cast_x_wo<<<dim3((n4x + n4w + 255) / 256), 256, 0, stream>>>(
      (const float4*)x, (const float4*)Wo, (ushort4*)x16, (ushort4*)wo16, n4x, n4w);
  cast_t<<<dim3(DM / 64, DM / 64, 3), 256, 0, stream>>>(
      Wq, Wk, Wv, wqT, wkT, wvT);

  const float scale = 0.08838834764831845f;  // 1/sqrt(128)

  // MT = Wk^T*Wq || G = Wo*Wv    [2048x2048 each], 512 blocks (full fill)
  k_mt_g<<<dim3(DM / 128, DM / 128, 2), 256, 0, stream>>>(
      wkT, wqT, wo16, wvT, MT, G);
  // y = x*M                      512 blocks (1 clean round)
  k_y<<<dim3(BSZ / 128, DM / 128, 1), 256, 0, stream>>>(x16, MT, y);
  // uT (512) + causal scores (272 triangular-packed): 784 uniform blocks
  k_su<<<dim3(784, 1, 1), 256, 0, stream>>>(G, x16, y, uT, scores, scale);

  softmax_causal<<<dim3(NB * SQ), 256, 0, stream>>>(scores, probs);

  // out[b*2048+s][i] = sum_t P_b[s,t] * uT[i][b*2048+t]  (fp32, K-limited,
  // complementary-row pairing at 2 blocks/CU)
  k_out<<<dim3(8, DM / 128, 4), 256, 0, stream>>>(probs, uT, out);
}

// Round 18
// 209.004 us; speedup vs baseline: 1.0113x; 1.0113x over previous
//
#include <hip/hip_runtime.h>

// Problem constants (B=2, S=2048, D=2048), all tile-divisible.
#define DM  2048
#define SQ  2048
#define NB  2
#define BSZ (NB * SQ)   // 4096 flattened tokens

typedef _Float16 f16x8 __attribute__((ext_vector_type(8)));
typedef __attribute__((ext_vector_type(4))) float f32x4;

#define ASG(p) (const __attribute__((address_space(1))) void*)(p)
#define ASL(p) (__attribute__((address_space(3))) void*)(p)

__device__ __forceinline__ unsigned short f2h(float f) {
  union { _Float16 h; unsigned short u; } x;
  x.h = (_Float16)f;  // v_cvt_f16_f32, RNE
  return x.u;
}
__device__ __forceinline__ float h2f(unsigned short u) {
  union { unsigned short u; _Float16 h; } x;
  x.u = u;
  return (float)x.h;
}

// ---- straight fp32->fp16 cast: x (n4x float4s) then Wo (n4w), contiguous out.
__global__ __launch_bounds__(256) void cast_x_wo(const float4* __restrict__ x,
                                                 const float4* __restrict__ wo,
                                                 ushort4* __restrict__ outx,
                                                 ushort4* __restrict__ outwo,
                                                 int n4x, int n4w) {
  int i = blockIdx.x * 256 + threadIdx.x;
  float4 v;
  ushort4* dst;
  int j;
  if (i < n4x) { v = x[i]; dst = outx; j = i; }
  else { j = i - n4x; if (j >= n4w) return; v = wo[j]; dst = outwo; }
  ushort4 h;
  h.x = f2h(v.x); h.y = f2h(v.y); h.z = f2h(v.z); h.w = f2h(v.w);
  dst[j] = h;
}

// ---- transpose-cast: W f32 [2048][2048] (d,e) -> WT fp16 [2048][2048] (e,d).
// 64x64 tiles, 256 threads. z selects {Wq,Wk,Wv}.
__global__ __launch_bounds__(256) void cast_t(const float* __restrict__ wq,
                                              const float* __restrict__ wk,
                                              const float* __restrict__ wv,
                                              unsigned short* __restrict__ wqT,
                                              unsigned short* __restrict__ wkT,
                                              unsigned short* __restrict__ wvT) {
  __shared__ unsigned short tile[64][66];
  const float* in = (blockIdx.z == 0) ? wq : (blockIdx.z == 1) ? wk : wv;
  unsigned short* outT = (blockIdx.z == 0) ? wqT : (blockIdx.z == 1) ? wkT : wvT;
  const int tid = threadIdx.x;
  const int d0 = blockIdx.x * 64, e0 = blockIdx.y * 64;
  const int r = tid >> 4;          // 0..15
  const int c = (tid & 15) * 4;    // 0..60
#pragma unroll
  for (int p = 0; p < 4; p++) {
    const int dl = r + p * 16;
    float4 v = *(const float4*)&in[(long)(d0 + dl) * DM + e0 + c];
    tile[c + 0][dl] = f2h(v.x);
    tile[c + 1][dl] = f2h(v.y);
    tile[c + 2][dl] = f2h(v.z);
    tile[c + 3][dl] = f2h(v.w);
  }
  __syncthreads();
  const int r2 = tid >> 3;         // 0..31
  const int c2 = (tid & 7) * 8;    // 0..56
#pragma unroll
  for (int p = 0; p < 2; p++) {
    const int el = r2 + p * 32;
    union { uint4 u4; unsigned short us[8]; } o;
#pragma unroll
    for (int k = 0; k < 8; k++) o.us[k] = tile[el][c2 + k];
    *(uint4*)&outT[(long)(e0 + el) * DM + d0 + c2] = o.u4;
  }
}

#define SB() __builtin_amdgcn_sched_barrier(0)
#define BARX() do { SB(); __builtin_amdgcn_s_barrier(); SB(); } while (0)

// ============================================================================
// 128x128 GEMM engine body (R11 schedule EXACTLY — verified race-free over
// R11-R17 replays). 4 waves (2Mx2N) per tile-stream, per-wave 64x64, BK=64,
// dbuf 2x32KB LDS, XOR swizzle (16B slot ^= row&7) both-sides (rule #21).
// Windows/hazards/vmcnt(6)/(0) ledger: see R11 commentary.
// tid is the caller's index within the 256-thread tile-stream; when two
// streams share a 512-thread block, s_barrier couples them — SAFE iff both
// streams execute identical barrier sequences (same NT).
// ============================================================================
#define STAGEK(BUFL, REG, U, T) do { \
    const unsigned short* G_ = (REG) ? Bb : Ab; \
    const int ldG_ = (REG) ? ldB : ldA; \
    const int r0_ = ((REG) ? bn0 : bm0) + (U) * 32; \
    const long k0_ = (long)((T) << 6); \
    char* db_ = ldsb + (BUFL) * 32768 + (REG) * 16384 + (U) * 4096 + tid * 16; \
    const unsigned short* s_ = G_ + (long)(r0_ + srow) * ldG_ + k0_ + scsw; \
    __builtin_amdgcn_global_load_lds(ASG(s_), ASL(db_), 16, 0, 0); \
  } while (0)

#define LDAK(BUFL, MH, Af) do { \
    const char* ba_ = ldsb + (BUFL) * 32768 + (wm * 64 + (MH) * 32) * 128 + arow; \
    _Pragma("unroll") for (int mm_ = 0; mm_ < 2; mm_++) { \
      Af[mm_][0] = *(const f16x8*)(ba_ + mm_ * 2048 + sl0); \
      Af[mm_][1] = *(const f16x8*)(ba_ + mm_ * 2048 + sl1); } \
  } while (0)

#define LDBK(BUFL, NH, Bf) do { \
    const char* bb_ = ldsb + (BUFL) * 32768 + 16384 + (wn * 64 + (NH) * 32) * 128 + arow; \
    _Pragma("unroll") for (int nn_ = 0; nn_ < 2; nn_++) { \
      Bf[nn_][0] = *(const f16x8*)(bb_ + nn_ * 2048 + sl0); \
      Bf[nn_][1] = *(const f16x8*)(bb_ + nn_ * 2048 + sl1); } \
  } while (0)

#define PHK(Af, Bf, MH, NH) do { \
    __builtin_amdgcn_s_setprio(1); \
    _Pragma("unroll") for (int mm_ = 0; mm_ < 2; mm_++) \
    _Pragma("unroll") for (int nn_ = 0; nn_ < 2; nn_++) \
    _Pragma("unroll") for (int ks_ = 0; ks_ < 2; ks_++) \
      acc[(MH) * 2 + mm_][(NH) * 2 + nn_] = __builtin_amdgcn_mfma_f32_16x16x32_f16( \
          Af[mm_][ks_], Bf[nn_][ks_], acc[(MH) * 2 + mm_][(NH) * 2 + nn_], 0, 0, 0); \
    __builtin_amdgcn_s_setprio(0); \
  } while (0)

#define GROUPK(BUFL, T) do { \
    LDAK(BUFL, 0, a0); LDBK(BUFL, 0, b0); \
    LDAK(BUFL, 1, a1); \
    if ((T) + 1 < NT) { STAGEK((BUFL) ^ 1, 1, 2, (T) + 1); STAGEK((BUFL) ^ 1, 1, 3, (T) + 1); } \
    PHK(a0, b0, 0, 0); \
    BARX(); \
    LDBK(BUFL, 1, b1); \
    PHK(a1, b0, 1, 0); \
    BARX(); \
    if ((T) + 2 < NT) { STAGEK(BUFL, 0, 0, (T) + 2); STAGEK(BUFL, 0, 1, (T) + 2); \
                        STAGEK(BUFL, 0, 2, (T) + 2); STAGEK(BUFL, 0, 3, (T) + 2); } \
    PHK(a1, b1, 1, 1); \
    BARX(); \
    if ((T) + 2 < NT) { STAGEK(BUFL, 1, 0, (T) + 2); STAGEK(BUFL, 1, 1, (T) + 2); } \
    PHK(a0, b1, 0, 1); \
    SB(); \
    if ((T) + 1 < NT) { \
      if ((T) + 1 == NT - 1) { asm volatile("s_waitcnt vmcnt(0)" ::: "memory"); } \
      else                   { asm volatile("s_waitcnt vmcnt(6)" ::: "memory"); } \
    } \
    __builtin_amdgcn_s_barrier(); \
    SB(); \
  } while (0)

template <int OM>
__device__ __forceinline__ void gemm128_body(
    char* ldsb, int tid, const unsigned short* __restrict__ Ab,
    const unsigned short* __restrict__ Bb,
    float* __restrict__ Cf, unsigned short* __restrict__ Ch, long cb,
    int NT, int ldA, int ldB, int ldC, int bm0, int bn0, float alpha) {
  const int lane = tid & 63, wid = tid >> 6;
  const int wm = wid >> 1, wn = wid & 1;
  const int fr = lane & 15, fq = lane >> 4;

  const int sl0 = ((fq ^ (fr & 7)) << 4);
  const int sl1 = (((4 + fq) ^ (fr & 7)) << 4);
  const int arow = fr << 7;

  const int srow = tid >> 3;                       // [0,32)
  const int scsw = ((tid & 7) ^ (srow & 7)) << 3;  // inverse-swizzled global col

  f32x4 acc[4][4];
#pragma unroll
  for (int m = 0; m < 4; m++)
#pragma unroll
    for (int n = 0; n < 4; n++)
#pragma unroll
      for (int r = 0; r < 4; r++) acc[m][n][r] = 0.f;

  f16x8 a0[2][2], a1[2][2], b0[2][2], b1[2][2];

  STAGEK(0, 0, 0, 0); STAGEK(0, 0, 1, 0); STAGEK(0, 0, 2, 0); STAGEK(0, 0, 3, 0);
  STAGEK(0, 1, 0, 0); STAGEK(0, 1, 1, 0); STAGEK(0, 1, 2, 0); STAGEK(0, 1, 3, 0);
  STAGEK(1, 0, 0, 1); STAGEK(1, 0, 1, 1); STAGEK(1, 0, 2, 1); STAGEK(1, 0, 3, 1);
  STAGEK(1, 1, 0, 1); STAGEK(1, 1, 1, 1);
  asm volatile("s_waitcnt vmcnt(6)" ::: "memory");
  __builtin_amdgcn_s_barrier();
  SB();

  for (int t = 0; t < NT; t += 2) {
    GROUPK(0, t);
    GROUPK(1, t + 1);
  }

#pragma unroll
  for (int mh = 0; mh < 2; mh++)
#pragma unroll
    for (int mm = 0; mm < 2; mm++)
#pragma unroll
      for (int nh = 0; nh < 2; nh++)
#pragma unroll
        for (int nn = 0; nn < 2; nn++) {
          const int col = bn0 + wn * 64 + nh * 32 + nn * 16 + fr;
#pragma unroll
          for (int r = 0; r < 4; r++) {
            const long row = (long)bm0 + wm * 64 + mh * 32 + mm * 16 + fq * 4 + r;
            const long ci = cb + row * ldC + col;
            const float vv = acc[mh * 2 + mm][nh * 2 + nn][r] * alpha;
            if constexpr (OM == 0) Cf[ci] = vv;
            else                   Ch[ci] = f2h(vv);
          }
        }
}

// Merged dispatch A: MT = Wk^T*Wq fold (z=0) || G = Wo*Wv fold (z=1).
// 512 blocks = full fill. All operands [2048][2048] fp16 K-contig.
__global__ __launch_bounds__(256, 2) void k_mt_g(
    const unsigned short* __restrict__ wkT, const unsigned short* __restrict__ wqT,
    const unsigned short* __restrict__ wo16, const unsigned short* __restrict__ wvT,
    unsigned short* __restrict__ MT, unsigned short* __restrict__ G) {
  __shared__ __align__(16) char ldsarr[65536];
  const int bm0 = blockIdx.x * 128;
  const int bn0 = blockIdx.y * 128;
  if (blockIdx.z == 0)
    gemm128_body<1>(ldsarr, threadIdx.x, wkT, wqT, nullptr, MT, 0L,
                    DM >> 6, DM, DM, DM, bm0, bn0, 1.0f);
  else
    gemm128_body<1>(ldsarr, threadIdx.x, wo16, wvT, nullptr, G, 0L,
                    DM >> 6, DM, DM, DM, bm0, bn0, 1.0f);
}

// Merged dispatch B: y = x*(MT)^T (z=0) || uT = G*x^T (z=1). 1024 blocks
// = 2 clean full-rate rounds.
__global__ __launch_bounds__(256, 2) void k_y_ut(
    const unsigned short* __restrict__ x16, const unsigned short* __restrict__ MT,
    const unsigned short* __restrict__ G,
    unsigned short* __restrict__ y, unsigned short* __restrict__ uT) {
  __shared__ __align__(16) char ldsarr[65536];
  if (blockIdx.z == 0) {
    const int bm0 = blockIdx.x * 128;   // s: 32
    const int bn0 = blockIdx.y * 128;   // f: 16
    gemm128_body<1>(ldsarr, threadIdx.x, x16, MT, nullptr, y, 0L,
                    DM >> 6, DM, DM, DM, bm0, bn0, 1.0f);
  } else {
    const int bm0 = blockIdx.y * 128;   // i: 16
    const int bn0 = blockIdx.x * 128;   // t: 32
    gemm128_body<1>(ldsarr, threadIdx.x, G, x16, nullptr, uT, 0L,
                    DM >> 6, DM, DM, BSZ, bm0, bn0, 1.0f);
  }
}

// Scores, two tile-streams per block (R18): 136 blocks x 512 threads.
// Each 256-thread half runs the verified engine on its OWN causal tile in
// its OWN 64KB LDS half -> 8 waves/CU from ONE block = shared-rate for both
// streams (the 272-tile dispatch previously ran lone-block half-rate).
// Barrier safety: both halves have identical NT=32 -> identical barrier
// sequences; vmcnt/lgkmcnt are per-wave; LDS + outputs disjoint.
// Tile index = blockIdx.x + h*136 in [0,272): z = idx/136 (batch),
// u = idx%136 triangular -> (r,c) lower-triangle 128x128 tile.
__global__ __launch_bounds__(512, 1) void k_scores_p(
    const unsigned short* __restrict__ y, const unsigned short* __restrict__ x16,
    unsigned short* __restrict__ scores, float scale) {
  __shared__ __align__(16) char ldsarr[131072];
  const int h = threadIdx.x >> 8;       // wave-uniform (waves 0-3 / 4-7)
  const int tid = threadIdx.x & 255;
  const int idx = blockIdx.x + h * 136; // 0..271
  const long z = idx / 136;
  const int u = idx % 136;
  const int r = (int)((sqrtf(8.f * (float)u + 1.f) - 1.f) * 0.5f);
  const int c = u - ((r * (r + 1)) >> 1);
  const unsigned short* Ab = y   + z * (long)SQ * DM;
  const unsigned short* Bb = x16 + z * (long)SQ * DM;
  gemm128_body<1>(ldsarr + h * 65536, tid, Ab, Bb, nullptr, scores,
                  z * (long)SQ * SQ, DM >> 6, DM, DM, SQ, r * 128, c * 128, scale);
}

// PV/out, complementary-row pairing at full occupancy (R16, kept): grid
// (8,16,4) = 512 blocks (2/CU). z&1 = batch; z>>1 selects row x or 15-x.
// Launch pairing (i,i+256) -> each CU gets rows x and 15-x = uniform 34
// K-tiles. K-limited: NT = 2(row+1), even, >=2.
__global__ __launch_bounds__(256, 2) void k_out(
    const unsigned short* __restrict__ probs, const unsigned short* __restrict__ uT,
    float* __restrict__ out) {
  __shared__ __align__(16) char ldsarr[65536];
  const int x = blockIdx.x;            // 0..7
  const int bn0 = blockIdx.y * 128;
  const long z = blockIdx.z & 1;       // batch
  const int row = (blockIdx.z >> 1) ? (15 - x) : x;
  const unsigned short* Ab = probs + z * (long)SQ * SQ;
  const unsigned short* Bb = uT + z * 2048;
  gemm128_body<0>(ldsarr, threadIdx.x, Ab, Bb, out, nullptr, z * (long)SQ * DM,
                  2 * (row + 1), SQ, BSZ, DM, 128 * row, bn0, 1.0f);
}

// ---- causal row softmax: scores fp16 [NB*SQ][SQ] -> probs fp16, zeros t>s.
__global__ __launch_bounds__(256) void softmax_causal(const unsigned short* __restrict__ sc,
                                                      unsigned short* __restrict__ pr) {
  const int row = blockIdx.x;       // b*SQ + s
  const int s = row & (SQ - 1);
  const long base = (long)row * SQ;
  const int n = s + 1;              // valid prefix length
  const int tid = threadIdx.x;
  const int lane = tid & 63;
  const int wv = tid >> 6;
  const int e0 = tid * 8;
  __shared__ float red[4];

  union { uint4 u4; unsigned short us[8]; } in, ou;
  in.u4 = *(const uint4*)&sc[base + e0];

  float v[8];
  float mx = -3.0e38f;
#pragma unroll
  for (int j = 0; j < 8; j++) {
    v[j] = (e0 + j < n) ? h2f(in.us[j]) : -3.0e38f;  // mask BEFORE use
    mx = fmaxf(mx, v[j]);
  }
#pragma unroll
  for (int o = 32; o >= 1; o >>= 1) mx = fmaxf(mx, __shfl_xor(mx, o));
  if (lane == 0) red[wv] = mx;
  __syncthreads();
  mx = fmaxf(fmaxf(red[0], red[1]), fmaxf(red[2], red[3]));
  __syncthreads();

  float sum = 0.f;
#pragma unroll
  for (int j = 0; j < 8; j++) {
    v[j] = (e0 + j < n) ? __expf(v[j] - mx) : 0.f;
    sum += v[j];
  }
#pragma unroll
  for (int o = 32; o >= 1; o >>= 1) sum += __shfl_xor(sum, o);
  if (lane == 0) red[wv] = sum;
  __syncthreads();
  const float inv = 1.f / (red[0] + red[1] + red[2] + red[3]);
#pragma unroll
  for (int j = 0; j < 8; j++) ou.us[j] = (e0 + j < n) ? f2h(v[j] * inv) : (unsigned short)0;
  *(uint4*)&pr[base + e0] = ou.u4;
}

extern "C" void kernel_launch(void* const* d_in, const int* in_sizes, int n_in,
                              void* d_out, int out_size, void* d_ws, size_t ws_size,
                              hipStream_t stream) {
  (void)in_sizes; (void)n_in; (void)out_size; (void)ws_size;
  const float* x  = (const float*)d_in[0];
  // d_in[1] = mask: exactly causal-additive(-1e9) -> implemented structurally.
  const float* Wq = (const float*)d_in[2];
  const float* Wk = (const float*)d_in[3];
  const float* Wv = (const float*)d_in[4];
  const float* Wo = (const float*)d_in[5];
  float* out = (float*)d_out;

  const long ELx = (long)BSZ * DM;  // 8,388,608
  const long ELw = (long)DM * DM;   // 4,194,304

  char* ws = (char*)d_ws;
  size_t off = 0;
  auto take = [&](size_t bytes) { void* p = ws + off; off += bytes; return p; };

  unsigned short* x16  = (unsigned short*)take(ELx * 2);  // dead after k_scores_p
  unsigned short* wqT  = (unsigned short*)take(ELw * 2);  // dead after k_mt_g
  unsigned short* wkT  = (unsigned short*)take(ELw * 2);  // dead after k_mt_g
  unsigned short* wvT  = (unsigned short*)take(ELw * 2);  // dead after k_mt_g
  unsigned short* wo16 = (unsigned short*)take(ELw * 2);  // dead after k_mt_g
  unsigned short* MT   = (unsigned short*)take(ELw * 2);  // dead after k_y_ut
  unsigned short* G    = (unsigned short*)take(ELw * 2);  // dead after k_y_ut
  unsigned short* y    = (unsigned short*)take(ELx * 2);  // dead after k_scores_p
  unsigned short* uT   = (unsigned short*)take(ELx * 2);  // live till k_out
  unsigned short* probs = (unsigned short*)take((long)NB * SQ * SQ * 2);
  // scores (16 MiB = NB*SQ*SQ fp16) aliases wqT∪wkT exactly (both dead after
  // k_mt_g; scores written two dispatches later — stream-ordered).
  unsigned short* scores = wqT;

  const int n4x = (int)(ELx / 4), n4w = (int)(ELw / 4);
  cast_x_wo<<<dim3((n4x + n4w + 255) / 256), 256, 0, stream>>>(
      (const float4*)x, (const float4*)Wo, (ushort4*)x16, (ushort4*)wo16, n4x, n4w);
  cast_t<<<dim3(DM / 64, DM / 64, 3), 256, 0, stream>>>(
      Wq, Wk, Wv, wqT, wkT, wvT);

  const float scale = 0.08838834764831845f;  // 1/sqrt(128)

  // MT = Wk^T*Wq || G = Wo*Wv    [2048x2048 each], 512 blocks (full fill)
  k_mt_g<<<dim3(DM / 128, DM / 128, 2), 256, 0, stream>>>(
      wkT, wqT, wo16, wvT, MT, G);
  // y = x*M || uT = G*x^T        1024 blocks (2 full rounds)
  k_y_ut<<<dim3(BSZ / 128, DM / 128, 2), 256, 0, stream>>>(
      x16, MT, G, y, uT);
  // scores: 136 blocks x 512 thr, 2 causal tiles per block (shared-rate)
  k_scores_p<<<dim3(136, 1, 1), 512, 0, stream>>>(y, x16, scores, scale);

  softmax_causal<<<dim3(NB * SQ), 256, 0, stream>>>(scores, probs);

  // out[b*2048+s][i] = sum_t P_b[s,t] * uT[i][b*2048+t]  (fp32, K-limited,
  // complementary-row pairing at 2 blocks/CU)
  k_out<<<dim3(8, DM / 128, 4), 256, 0, stream>>>(probs, uT, out);
}

// Round 19
// 204.678 us; speedup vs baseline: 1.0327x; 1.0211x over previous
//
#include <hip/hip_runtime.h>

// Problem constants (B=2, S=2048, D=2048), all tile-divisible.
#define DM  2048
#define SQ  2048
#define NB  2
#define BSZ (NB * SQ)   // 4096 flattened tokens

typedef _Float16 f16x8 __attribute__((ext_vector_type(8)));
typedef __attribute__((ext_vector_type(4))) float f32x4;

#define ASG(p) (const __attribute__((address_space(1))) void*)(p)
#define ASL(p) (__attribute__((address_space(3))) void*)(p)

__device__ __forceinline__ unsigned short f2h(float f) {
  union { _Float16 h; unsigned short u; } x;
  x.h = (_Float16)f;  // v_cvt_f16_f32, RNE
  return x.u;
}
__device__ __forceinline__ float h2f(unsigned short u) {
  union { unsigned short u; _Float16 h; } x;
  x.u = u;
  return (float)x.h;
}

// ============================================================================
// Merged input cast (R19): ONE dispatch does all fp32->fp16 prep.
//   blocks [0, 12288): straight cast of x (8192 blocks) then Wo (4096),
//     256 float4 per block.
//   blocks [12288, 15360): 64x64 LDS transpose-cast of {Wq,Wk,Wv} -> K-major.
// Removes one launch tail; both paths HBM-bound.
// ============================================================================
__global__ __launch_bounds__(256) void cast_all(
    const float4* __restrict__ x, const float4* __restrict__ wq,
    const float* __restrict__ wqf, const float* __restrict__ wkf,
    const float* __restrict__ wvf, const float4* __restrict__ wo,
    ushort4* __restrict__ outx, ushort4* __restrict__ outwo,
    unsigned short* __restrict__ wqT, unsigned short* __restrict__ wkT,
    unsigned short* __restrict__ wvT) {
  (void)wq;
  const int b = blockIdx.x;
  if (b < 12288) {
    // straight: i in [0, 3145728) float4s; x first (2097152), then Wo.
    const int i = b * 256 + threadIdx.x;
    float4 v;
    ushort4* dst;
    int j;
    if (i < 2097152) { v = x[i]; dst = outx; j = i; }
    else { j = i - 2097152; v = wo[j]; dst = outwo; }
    ushort4 h;
    h.x = f2h(v.x); h.y = f2h(v.y); h.z = f2h(v.z); h.w = f2h(v.w);
    dst[j] = h;
    return;
  }
  // transpose path
  __shared__ unsigned short tile[64][66];
  const int u = b - 12288;          // 0..3071
  const int z = u >> 10;            // 0..2 selects {Wq,Wk,Wv}
  const int t = u & 1023;
  const float* in = (z == 0) ? wqf : (z == 1) ? wkf : wvf;
  unsigned short* outT = (z == 0) ? wqT : (z == 1) ? wkT : wvT;
  const int tid = threadIdx.x;
  const int d0 = (t >> 5) * 64, e0 = (t & 31) * 64;
  const int r = tid >> 4;           // 0..15
  const int c = (tid & 15) * 4;     // 0..60
#pragma unroll
  for (int p = 0; p < 4; p++) {
    const int dl = r + p * 16;
    float4 v = *(const float4*)&in[(long)(d0 + dl) * DM + e0 + c];
    tile[c + 0][dl] = f2h(v.x);
    tile[c + 1][dl] = f2h(v.y);
    tile[c + 2][dl] = f2h(v.z);
    tile[c + 3][dl] = f2h(v.w);
  }
  __syncthreads();
  const int r2 = tid >> 3;          // 0..31
  const int c2 = (tid & 7) * 8;     // 0..56
#pragma unroll
  for (int p = 0; p < 2; p++) {
    const int el = r2 + p * 32;
    union { uint4 u4; unsigned short us[8]; } o;
#pragma unroll
    for (int k = 0; k < 8; k++) o.us[k] = tile[el][c2 + k];
    *(uint4*)&outT[(long)(e0 + el) * DM + d0 + c2] = o.u4;
  }
}

#define SB() __builtin_amdgcn_sched_barrier(0)
#define BARX() do { SB(); __builtin_amdgcn_s_barrier(); SB(); } while (0)

// ============================================================================
// 128x128 GEMM engine body (R11 schedule EXACTLY — verified race-free over
// R11-R18 replays). 4 waves (2Mx2N), per-wave 64x64, BK=64, dbuf 2x32KB LDS,
// XOR swizzle (16B slot ^= row&7) both-sides (rule #21).
// Windows/hazards/vmcnt(6)/(0) ledger: see R11 commentary.
// Measured model (R10-R18): time/K-tile/CU = LDSbytes/128B + FLOP/3380 —
// fully serialized, invariant to schedule/occupancy permutations (8 exps).
// ============================================================================
#define STAGEK(BUFL, REG, U, T) do { \
    const unsigned short* G_ = (REG) ? Bb : Ab; \
    const int ldG_ = (REG) ? ldB : ldA; \
    const int r0_ = ((REG) ? bn0 : bm0) + (U) * 32; \
    const long k0_ = (long)((T) << 6); \
    char* db_ = ldsb + (BUFL) * 32768 + (REG) * 16384 + (U) * 4096 + tid * 16; \
    const unsigned short* s_ = G_ + (long)(r0_ + srow) * ldG_ + k0_ + scsw; \
    __builtin_amdgcn_global_load_lds(ASG(s_), ASL(db_), 16, 0, 0); \
  } while (0)

#define LDAK(BUFL, MH, Af) do { \
    const char* ba_ = ldsb + (BUFL) * 32768 + (wm * 64 + (MH) * 32) * 128 + arow; \
    _Pragma("unroll") for (int mm_ = 0; mm_ < 2; mm_++) { \
      Af[mm_][0] = *(const f16x8*)(ba_ + mm_ * 2048 + sl0); \
      Af[mm_][1] = *(const f16x8*)(ba_ + mm_ * 2048 + sl1); } \
  } while (0)

#define LDBK(BUFL, NH, Bf) do { \
    const char* bb_ = ldsb + (BUFL) * 32768 + 16384 + (wn * 64 + (NH) * 32) * 128 + arow; \
    _Pragma("unroll") for (int nn_ = 0; nn_ < 2; nn_++) { \
      Bf[nn_][0] = *(const f16x8*)(bb_ + nn_ * 2048 + sl0); \
      Bf[nn_][1] = *(const f16x8*)(bb_ + nn_ * 2048 + sl1); } \
  } while (0)

#define PHK(Af, Bf, MH, NH) do { \
    __builtin_amdgcn_s_setprio(1); \
    _Pragma("unroll") for (int mm_ = 0; mm_ < 2; mm_++) \
    _Pragma("unroll") for (int nn_ = 0; nn_ < 2; nn_++) \
    _Pragma("unroll") for (int ks_ = 0; ks_ < 2; ks_++) \
      acc[(MH) * 2 + mm_][(NH) * 2 + nn_] = __builtin_amdgcn_mfma_f32_16x16x32_f16( \
          Af[mm_][ks_], Bf[nn_][ks_], acc[(MH) * 2 + mm_][(NH) * 2 + nn_], 0, 0, 0); \
    __builtin_amdgcn_s_setprio(0); \
  } while (0)

#define GROUPK(BUFL, T) do { \
    LDAK(BUFL, 0, a0); LDBK(BUFL, 0, b0); \
    LDAK(BUFL, 1, a1); \
    if ((T) + 1 < NT) { STAGEK((BUFL) ^ 1, 1, 2, (T) + 1); STAGEK((BUFL) ^ 1, 1, 3, (T) + 1); } \
    PHK(a0, b0, 0, 0); \
    BARX(); \
    LDBK(BUFL, 1, b1); \
    PHK(a1, b0, 1, 0); \
    BARX(); \
    if ((T) + 2 < NT) { STAGEK(BUFL, 0, 0, (T) + 2); STAGEK(BUFL, 0, 1, (T) + 2); \
                        STAGEK(BUFL, 0, 2, (T) + 2); STAGEK(BUFL, 0, 3, (T) + 2); } \
    PHK(a1, b1, 1, 1); \
    BARX(); \
    if ((T) + 2 < NT) { STAGEK(BUFL, 1, 0, (T) + 2); STAGEK(BUFL, 1, 1, (T) + 2); } \
    PHK(a0, b1, 0, 1); \
    SB(); \
    if ((T) + 1 < NT) { \
      if ((T) + 1 == NT - 1) { asm volatile("s_waitcnt vmcnt(0)" ::: "memory"); } \
      else                   { asm volatile("s_waitcnt vmcnt(6)" ::: "memory"); } \
    } \
    __builtin_amdgcn_s_barrier(); \
    SB(); \
  } while (0)

template <int OM>
__device__ __forceinline__ void gemm128_body(
    char* ldsb, int tid, const unsigned short* __restrict__ Ab,
    const unsigned short* __restrict__ Bb,
    float* __restrict__ Cf, unsigned short* __restrict__ Ch, long cb,
    int NT, int ldA, int ldB, int ldC, int bm0, int bn0, float alpha) {
  const int lane = tid & 63, wid = tid >> 6;
  const int wm = wid >> 1, wn = wid & 1;
  const int fr = lane & 15, fq = lane >> 4;

  const int sl0 = ((fq ^ (fr & 7)) << 4);
  const int sl1 = (((4 + fq) ^ (fr & 7)) << 4);
  const int arow = fr << 7;

  const int srow = tid >> 3;                       // [0,32)
  const int scsw = ((tid & 7) ^ (srow & 7)) << 3;  // inverse-swizzled global col

  f32x4 acc[4][4];
#pragma unroll
  for (int m = 0; m < 4; m++)
#pragma unroll
    for (int n = 0; n < 4; n++)
#pragma unroll
      for (int r = 0; r < 4; r++) acc[m][n][r] = 0.f;

  f16x8 a0[2][2], a1[2][2], b0[2][2], b1[2][2];

  STAGEK(0, 0, 0, 0); STAGEK(0, 0, 1, 0); STAGEK(0, 0, 2, 0); STAGEK(0, 0, 3, 0);
  STAGEK(0, 1, 0, 0); STAGEK(0, 1, 1, 0); STAGEK(0, 1, 2, 0); STAGEK(0, 1, 3, 0);
  STAGEK(1, 0, 0, 1); STAGEK(1, 0, 1, 1); STAGEK(1, 0, 2, 1); STAGEK(1, 0, 3, 1);
  STAGEK(1, 1, 0, 1); STAGEK(1, 1, 1, 1);
  asm volatile("s_waitcnt vmcnt(6)" ::: "memory");
  __builtin_amdgcn_s_barrier();
  SB();

  for (int t = 0; t < NT; t += 2) {
    GROUPK(0, t);
    GROUPK(1, t + 1);
  }

#pragma unroll
  for (int mh = 0; mh < 2; mh++)
#pragma unroll
    for (int mm = 0; mm < 2; mm++)
#pragma unroll
      for (int nh = 0; nh < 2; nh++)
#pragma unroll
        for (int nn = 0; nn < 2; nn++) {
          const int col = bn0 + wn * 64 + nh * 32 + nn * 16 + fr;
#pragma unroll
          for (int r = 0; r < 4; r++) {
            const long row = (long)bm0 + wm * 64 + mh * 32 + mm * 16 + fq * 4 + r;
            const long ci = cb + row * ldC + col;
            const float vv = acc[mh * 2 + mm][nh * 2 + nn][r] * alpha;
            if constexpr (OM == 0) Cf[ci] = vv;
            else                   Ch[ci] = f2h(vv);
          }
        }
}

// Standalone wrapper (scores). CAUSAL: 0 none, 1 = skip bn0>bm0.
template <int OM, int CAUSAL>
__global__ __launch_bounds__(256, 2) void gemm128(
    const unsigned short* __restrict__ A, const unsigned short* __restrict__ B,
    float* __restrict__ Cf, unsigned short* __restrict__ Ch,
    int K, long sAb, long sBb, long sCb,
    int ldA, int ldB, int ldC, float alpha) {
  __shared__ __align__(16) char ldsarr[65536];
  const int bm0 = blockIdx.x * 128;
  const int bn0 = blockIdx.y * 128;
  if (CAUSAL == 1 && bn0 > bm0) return;  // fully masked; never read later
  const int z = blockIdx.z;
  gemm128_body<OM>(ldsarr, threadIdx.x, A + (long)z * sAb, B + (long)z * sBb,
                   Cf, Ch, (long)z * sCb, K >> 6, ldA, ldB, ldC, bm0, bn0, alpha);
}

// Merged dispatch A: MT = Wk^T*Wq fold (z=0) || G = Wo*Wv fold (z=1).
// 512 blocks = full fill. All operands [2048][2048] fp16 K-contig.
__global__ __launch_bounds__(256, 2) void k_mt_g(
    const unsigned short* __restrict__ wkT, const unsigned short* __restrict__ wqT,
    const unsigned short* __restrict__ wo16, const unsigned short* __restrict__ wvT,
    unsigned short* __restrict__ MT, unsigned short* __restrict__ G) {
  __shared__ __align__(16) char ldsarr[65536];
  const int bm0 = blockIdx.x * 128;
  const int bn0 = blockIdx.y * 128;
  if (blockIdx.z == 0)
    gemm128_body<1>(ldsarr, threadIdx.x, wkT, wqT, nullptr, MT, 0L,
                    DM >> 6, DM, DM, DM, bm0, bn0, 1.0f);
  else
    gemm128_body<1>(ldsarr, threadIdx.x, wo16, wvT, nullptr, G, 0L,
                    DM >> 6, DM, DM, DM, bm0, bn0, 1.0f);
}

// Merged dispatch B: y = x*(MT)^T (z=0) || uT = G*x^T (z=1). 1024 blocks
// = 2 clean full-rate rounds.
__global__ __launch_bounds__(256, 2) void k_y_ut(
    const unsigned short* __restrict__ x16, const unsigned short* __restrict__ MT,
    const unsigned short* __restrict__ G,
    unsigned short* __restrict__ y, unsigned short* __restrict__ uT) {
  __shared__ __align__(16) char ldsarr[65536];
  if (blockIdx.z == 0) {
    const int bm0 = blockIdx.x * 128;   // s: 32
    const int bn0 = blockIdx.y * 128;   // f: 16
    gemm128_body<1>(ldsarr, threadIdx.x, x16, MT, nullptr, y, 0L,
                    DM >> 6, DM, DM, DM, bm0, bn0, 1.0f);
  } else {
    const int bm0 = blockIdx.y * 128;   // i: 16
    const int bn0 = blockIdx.x * 128;   // t: 32
    gemm128_body<1>(ldsarr, threadIdx.x, G, x16, nullptr, uT, 0L,
                    DM >> 6, DM, DM, BSZ, bm0, bn0, 1.0f);
  }
}

// PV/out, complementary-row pairing at full occupancy (R16): grid (8,16,4) =
// 512 blocks (2/CU). z&1 = batch; z>>1 selects row x or 15-x. Launch pairing
// (i,i+256) -> each CU gets rows x and 15-x = uniform 34 K-tiles.
__global__ __launch_bounds__(256, 2) void k_out(
    const unsigned short* __restrict__ probs, const unsigned short* __restrict__ uT,
    float* __restrict__ out) {
  __shared__ __align__(16) char ldsarr[65536];
  const int x = blockIdx.x;            // 0..7
  const int bn0 = blockIdx.y * 128;
  const long z = blockIdx.z & 1;       // batch
  const int row = (blockIdx.z >> 1) ? (15 - x) : x;
  const unsigned short* Ab = probs + z * (long)SQ * SQ;
  const unsigned short* Bb = uT + z * 2048;
  gemm128_body<0>(ldsarr, threadIdx.x, Ab, Bb, out, nullptr, z * (long)SQ * DM,
                  2 * (row + 1), SQ, BSZ, DM, 128 * row, bn0, 1.0f);
}

// ---- causal row softmax: scores fp16 [NB*SQ][SQ] -> probs fp16, zeros t>s.
__global__ __launch_bounds__(256) void softmax_causal(const unsigned short* __restrict__ sc,
                                                      unsigned short* __restrict__ pr) {
  const int row = blockIdx.x;       // b*SQ + s
  const int s = row & (SQ - 1);
  const long base = (long)row * SQ;
  const int n = s + 1;              // valid prefix length
  const int tid = threadIdx.x;
  const int lane = tid & 63;
  const int wv = tid >> 6;
  const int e0 = tid * 8;
  __shared__ float red[4];

  union { uint4 u4; unsigned short us[8]; } in, ou;
  in.u4 = *(const uint4*)&sc[base + e0];

  float v[8];
  float mx = -3.0e38f;
#pragma unroll
  for (int j = 0; j < 8; j++) {
    v[j] = (e0 + j < n) ? h2f(in.us[j]) : -3.0e38f;  // mask BEFORE use
    mx = fmaxf(mx, v[j]);
  }
#pragma unroll
  for (int o = 32; o >= 1; o >>= 1) mx = fmaxf(mx, __shfl_xor(mx, o));
  if (lane == 0) red[wv] = mx;
  __syncthreads();
  mx = fmaxf(fmaxf(red[0], red[1]), fmaxf(red[2], red[3]));
  __syncthreads();

  float sum = 0.f;
#pragma unroll
  for (int j = 0; j < 8; j++) {
    v[j] = (e0 + j < n) ? __expf(v[j] - mx) : 0.f;
    sum += v[j];
  }
#pragma unroll
  for (int o = 32; o >= 1; o >>= 1) sum += __shfl_xor(sum, o);
  if (lane == 0) red[wv] = sum;
  __syncthreads();
  const float inv = 1.f / (red[0] + red[1] + red[2] + red[3]);
#pragma unroll
  for (int j = 0; j < 8; j++) ou.us[j] = (e0 + j < n) ? f2h(v[j] * inv) : (unsigned short)0;
  *(uint4*)&pr[base + e0] = ou.u4;
}

extern "C" void kernel_launch(void* const* d_in, const int* in_sizes, int n_in,
                              void* d_out, int out_size, void* d_ws, size_t ws_size,
                              hipStream_t stream) {
  (void)in_sizes; (void)n_in; (void)out_size; (void)ws_size;
  const float* x  = (const float*)d_in[0];
  // d_in[1] = mask: exactly causal-additive(-1e9) -> implemented structurally.
  const float* Wq = (const float*)d_in[2];
  const float* Wk = (const float*)d_in[3];
  const float* Wv = (const float*)d_in[4];
  const float* Wo = (const float*)d_in[5];
  float* out = (float*)d_out;

  const long ELx = (long)BSZ * DM;  // 8,388,608
  const long ELw = (long)DM * DM;   // 4,194,304

  char* ws = (char*)d_ws;
  size_t off = 0;
  auto take = [&](size_t bytes) { void* p = ws + off; off += bytes; return p; };

  unsigned short* x16  = (unsigned short*)take(ELx * 2);  // dead after scores
  unsigned short* wqT  = (unsigned short*)take(ELw * 2);  // dead after k_mt_g
  unsigned short* wkT  = (unsigned short*)take(ELw * 2);  // dead after k_mt_g
  unsigned short* wvT  = (unsigned short*)take(ELw * 2);  // dead after k_mt_g
  unsigned short* wo16 = (unsigned short*)take(ELw * 2);  // dead after k_mt_g
  unsigned short* MT   = (unsigned short*)take(ELw * 2);  // dead after k_y_ut
  unsigned short* G    = (unsigned short*)take(ELw * 2);  // dead after k_y_ut
  unsigned short* y    = (unsigned short*)take(ELx * 2);  // dead after scores
  unsigned short* uT   = (unsigned short*)take(ELx * 2);  // live till k_out
  unsigned short* probs = (unsigned short*)take((long)NB * SQ * SQ * 2);
  // scores (16 MiB = NB*SQ*SQ fp16) aliases wqT∪wkT exactly (both dead after
  // k_mt_g; scores written two dispatches later — stream-ordered).
  unsigned short* scores = wqT;

  // Merged cast: 12288 straight blocks (x, Wo) + 3072 transpose blocks.
  cast_all<<<dim3(15360, 1, 1), 256, 0, stream>>>(
      (const float4*)x, (const float4*)Wq, Wq, Wk, Wv, (const float4*)Wo,
      (ushort4*)x16, (ushort4*)wo16, wqT, wkT, wvT);

  const float scale = 0.08838834764831845f;  // 1/sqrt(128)

  // MT = Wk^T*Wq || G = Wo*Wv    [2048x2048 each], 512 blocks (full fill)
  k_mt_g<<<dim3(DM / 128, DM / 128, 2), 256, 0, stream>>>(
      wkT, wqT, wo16, wvT, MT, G);
  // y = x*M || uT = G*x^T        1024 blocks (2 full rounds)
  k_y_ut<<<dim3(BSZ / 128, DM / 128, 2), 256, 0, stream>>>(
      x16, MT, G, y, uT);
  // scores[b][s][t] = scale * sum_f y[s,f]*x[t,f]   (fp16, causal block-skip)
  gemm128<1, 1><<<dim3(SQ / 128, SQ / 128, NB), 256, 0, stream>>>(
      y, x16, nullptr, scores, DM, (long)SQ * DM, (long)SQ * DM,
      (long)SQ * SQ, DM, DM, SQ, scale);

  softmax_causal<<<dim3(NB * SQ), 256, 0, stream>>>(scores, probs);

  // out[b*2048+s][i] = sum_t P_b[s,t] * uT[i][b*2048+t]  (fp32, K-limited,
  // complementary-row pairing at 2 blocks/CU)
  k_out<<<dim3(8, DM / 128, 4), 256, 0, stream>>>(probs, uT, out);
}